// Round 5
// baseline (131.559 us; speedup 1.0000x reference)
//
#include <hip/hip_runtime.h>
#include <math.h>

#ifndef M_PI
#define M_PI 3.14159265358979323846
#endif

#define NWIN   400
#define NSHIFT 160
#define NMELS  80
#define NFRM   998
#define WLEN   160000
#define FPB    4
#define BPB    250          // frame-blocks per batch (249 full + 1 tail of 2)
#define EPSV   1.1920929e-07f

// workspace layout (floats)
#define WIN_OFF  0      // [400] Povey window
#define UMEL_OFF 512    // [256] mel coordinate of each bin
#define TWID_OFF 768    // [85*6] per-stage radix-4 twiddles (W1,W2,W3 as x,y)
#define WEXP_OFF 1280   // [128*2] untangle W[k]=e^{-i pi k/256}, k=0..127 (cos,-sin)
#define WS_FLOATS 1536  // 6144 B

// XOR swizzle on complex (float2) slot index: all 4 FFT stages hit the
// 4-lane-per-bank-pair floor for b64.
__device__ __forceinline__ int swz(int s) { return s ^ ((s >> 4) & 15); }

__global__ __launch_bounds__(128)
void setup_kernel(float* __restrict__ ws)
{
    const int gid = blockIdx.x * 128 + threadIdx.x;   // grid 8 x 128
    const double ML = 1127.0 * log(1.0 + 20.0 / 700.0);
    const double MH = 1127.0 * log(1.0 + 8000.0 / 700.0);
    const double DD = (MH - ML) / (double)(NMELS + 1);

    if (gid < NWIN) {
        double a = 0.5 - 0.5 * cos(2.0 * M_PI * (double)gid / 399.0);
        if (a < 0.0) a = 0.0;
        ws[WIN_OFF + gid] = (float)pow(a, 0.85);
    } else if (gid >= 512 && gid < 768) {
        int b = gid - 512;
        double mel = 1127.0 * log(1.0 + (double)b * 31.25 / 700.0);
        ws[UMEL_OFF + b] = (float)((mel - ML) / DD);
    } else if (gid >= 768 && gid < 853) {
        int e = gid - 768, st, j;
        if      (e < 64) { st = 0; j = e; }
        else if (e < 80) { st = 1; j = e - 64; }
        else if (e < 84) { st = 2; j = e - 80; }
        else             { st = 3; j = 0; }
        int Q = 64 >> (2 * st);
        double ang = -M_PI * (double)j / (2.0 * (double)Q);   // -2*pi*j/(4Q)
        float* t = ws + TWID_OFF + e * 6;
        t[0] = (float)cos(ang);       t[1] = (float)sin(ang);
        t[2] = (float)cos(2.0 * ang); t[3] = (float)sin(2.0 * ang);
        t[4] = (float)cos(3.0 * ang); t[5] = (float)sin(3.0 * ang);
    } else if (gid >= 896 && gid < 896 + 128) {
        int k = gid - 896;
        double th = M_PI * (double)k / 256.0;
        ws[WEXP_OFF + 2 * k]     = (float)cos(th);
        ws[WEXP_OFF + 2 * k + 1] = (float)(-sin(th));
    }
}

template<bool USE_TAB>
__global__ __launch_bounds__(256)
void fbank_kernel(const float* __restrict__ wav, float* __restrict__ out,
                  const float* __restrict__ ws)
{
    __shared__ __align__(16) float zbf[FPB][512];     // per-wave complex buffer
    __shared__ __align__(16) float wbuf[NWIN];        // Povey window
    __shared__ __align__(16) float ubuf[256];         // mel coordinate per bin
    __shared__ __align__(16) float acc[FPB][96];      // mel accumulators (ds_add_f32)
    __shared__ __align__(16) float res[NMELS * FPB];  // logmel [mel][frame-slot]

    const int tid  = threadIdx.x;
    const int lane = tid & 63;
    const int wv   = tid >> 6;                 // one wave per frame
    const int bb   = blockIdx.x / BPB;
    const int f0   = (blockIdx.x % BPB) * FPB;
    const bool valid = (f0 + wv) < NFRM;

    // ---- tables: stage from workspace, or (fallback) fast-intrinsic build ----
    if constexpr (USE_TAB) {
        ubuf[tid & 255] = ws[UMEL_OFF + (tid & 255)];
        wbuf[tid < NWIN ? tid : 0] = ws[WIN_OFF + (tid < NWIN ? tid : 0)];
        if (tid < NWIN - 256) wbuf[tid + 256] = ws[WIN_OFF + 256 + tid];
    } else {
        const float MLf = 1127.0f * __logf(1.0f + 20.0f / 700.0f);
        const float MHf = 1127.0f * __logf(1.0f + 8000.0f / 700.0f);
        const float DDf = (MHf - MLf) / (float)(NMELS + 1);
        float freq = (float)tid * 31.25f;
        ubuf[tid] = (1127.0f * __logf(1.0f + freq * (1.0f / 700.0f)) - MLf) / DDf;
        const float CW = (float)(2.0 * M_PI / 399.0);
        float a = fmaxf(0.5f - 0.5f * __cosf((float)tid * CW), 0.0f);
        wbuf[tid] = __powf(a, 0.85f);
        if (tid < NWIN - 256) {
            int n = tid + 256;
            float a2 = fmaxf(0.5f - 0.5f * __cosf((float)n * CW), 0.0f);
            wbuf[n] = __powf(a2, 0.85f);
        }
    }
    __syncthreads();

    float*  zf = zbf[wv];
    float2* zc = (float2*)zf;

    // zero this wave's mel accumulators (wave-private; DS in-order per wave)
    acc[wv][lane] = 0.0f;
    if (lane < 32) acc[wv][64 + lane] = 0.0f;

    // ---- preprocess: de-mean, pre-emphasis (2nd load), window; pack pairs ----
    if (valid) {
        const float* xp = wav + (size_t)bb * WLEN + (size_t)(f0 + wv) * NSHIFT;
        float xc[7], xm[7];
        float s = 0.0f;
        #pragma unroll
        for (int t = 0; t < 7; ++t) {
            int n = 64 * t + lane;
            bool vn = (t < 6 || lane < 16);
            xc[t] = vn ? xp[n] : 0.0f;
            xm[t] = (vn && n > 0) ? xp[n - 1] : 0.0f;   // L1-hit reload
            s += xc[t];
        }
        if (lane == 0) xm[0] = xc[0];                   // ref: prev[0] = x[0]
        #pragma unroll
        for (int off = 32; off > 0; off >>= 1) s += __shfl_xor(s, off, 64);
        const float mu3 = 0.03f * (s * (1.0f / (float)NWIN));
        #pragma unroll
        for (int t = 0; t < 7; ++t) {
            int n = 64 * t + lane;
            float y = 0.0f;
            if (t < 6 || lane < 16)
                y = (fmaf(-0.97f, xm[t], xc[t]) - mu3) * wbuf[n];
            zf[(swz(n >> 1) << 1) | (n & 1)] = y;       // n>=400 slots get 0
        }
        zf[(swz((448 + lane) >> 1) << 1) | (lane & 1)] = 0.0f;  // pad z[224..255]
    }

    // ---- 256-point radix-4 DIF FFT, in-place, digit-reversed output ----
    if (valid) {
        #pragma unroll
        for (int st = 0; st < 4; ++st) {
            const int Q = 64 >> (2 * st);                 // L/4
            int j  = lane & (Q - 1);
            int i0 = ((lane & ~(Q - 1)) << 2) + j;        // base + j
            float2 a0 = zc[swz(i0)];
            float2 a1 = zc[swz(i0 + Q)];
            float2 a2 = zc[swz(i0 + 2 * Q)];
            float2 a3 = zc[swz(i0 + 3 * Q)];
            float t0x = a0.x + a2.x, t0y = a0.y + a2.y;
            float t1x = a1.x + a3.x, t1y = a1.y + a3.y;
            float t2x = a0.x - a2.x, t2y = a0.y - a2.y;
            float t3x = a1.x - a3.x, t3y = a1.y - a3.y;
            float b0x = t0x + t1x, b0y = t0y + t1y;       // q=0
            float b2x = t0x - t1x, b2y = t0y - t1y;       // q=2
            float b1x = t2x + t3y, b1y = t2y - t3x;       // q=1: t2 - i*t3
            float b3x = t2x - t3y, b3y = t2y + t3x;       // q=3: t2 + i*t3
            float cn, sn, w2x, w2y, w3x, w3y;
            if constexpr (USE_TAB) {
                constexpr int TOFF[4] = {0, 64, 80, 84};
                const float* tw = ws + TWID_OFF + (TOFF[st] + j) * 6;
                cn = tw[0]; sn = tw[1]; w2x = tw[2]; w2y = tw[3]; w3x = tw[4]; w3y = tw[5];
            } else {
                float ang = (float)j * (float)(-M_PI / 2.0 / (double)Q);
                __sincosf(ang, &sn, &cn);
                w2x = cn * cn - sn * sn; w2y = 2.0f * cn * sn;
                w3x = w2x * cn - w2y * sn; w3y = w2x * sn + w2y * cn;
            }
            zc[swz(i0)]       = make_float2(b0x, b0y);
            zc[swz(i0 + Q)]   = make_float2(fmaf(b1x, cn,  -b1y * sn),  fmaf(b1x, sn,  b1y * cn));
            zc[swz(i0 + 2*Q)] = make_float2(fmaf(b2x, w2x, -b2y * w2y), fmaf(b2x, w2y, b2y * w2x));
            zc[swz(i0 + 3*Q)] = make_float2(fmaf(b3x, w3x, -b3y * w3y), fmaf(b3x, w3y, b3y * w3x));
        }
    }

    // ---- fused untangle + power + mel scatter ----
    // X[k] = E + W*O, X[256-k] = conj(E - W*O); p = |X|^2.
    // Each bin b (mel coord u, f=floor(u)) feeds mel f-1 with (1-d)*p and mel f
    // with d*p, d = u-f  (exact 2-triangle decomposition of the Kaldi bank).
    if (valid) {
        const int rl = ((lane & 3) << 6) | (((lane >> 2) & 3) << 4) | (((lane >> 4) & 3) << 2);
        #pragma unroll
        for (int r = 0; r < 2; ++r) {
            int k  = 64 * r + lane;
            int m8 = (256 - k) & 255;
            int rk = rl | r;
            int rm = ((m8 & 3) << 6) | (((m8 >> 2) & 3) << 4) | (((m8 >> 4) & 3) << 2) | ((m8 >> 6) & 3);
            float2 Zk = zc[swz(rk)];
            float2 Zm = zc[swz(rm)];
            float Sx = Zk.x + Zm.x, Sy = Zk.y - Zm.y;   // 2E
            float Ox = Zk.y + Zm.y, Oy = Zm.x - Zk.x;   // 2O
            float Wx, Wy;
            if constexpr (USE_TAB) {
                float2 w = ((const float2*)(ws + WEXP_OFF))[k];
                Wx = w.x; Wy = w.y;
            } else {
                __sincosf((float)k * (float)(-M_PI / 256.0), &Wy, &Wx);
            }
            float Ux = fmaf(Wx, Ox, -Wy * Oy), Uy = fmaf(Wx, Oy, Wy * Ox);  // 2*W*O
            float q1 = Sx + Ux, q2 = Sy + Uy;
            float q3 = Sx - Ux, q4 = Sy - Uy;
            float pk = 0.25f * fmaf(q1, q1, q2 * q2);
            float pm = 0.25f * fmaf(q3, q3, q4 * q4);
            {   // scatter bin k (k=0 auto-skipped: u<0)
                float u = ubuf[k];
                float ff = floorf(u);
                int   f  = (int)ff;
                float d  = u - ff;
                if (f >= 1 && f <= NMELS) atomicAdd(&acc[wv][f - 1], (1.0f - d) * pk);
                if (f >= 0 && f <  NMELS) atomicAdd(&acc[wv][f],     d * pk);
            }
            if (m8 != 0) {  // m8==0 <=> bin 256 (zero weight in ref)
                float u = ubuf[m8];
                float ff = floorf(u);
                int   f  = (int)ff;
                float d  = u - ff;
                if (f >= 1 && f <= NMELS) atomicAdd(&acc[wv][f - 1], (1.0f - d) * pm);
                if (f >= 0 && f <  NMELS) atomicAdd(&acc[wv][f],     d * pm);
            }
        }
        if (lane == 0) {   // bin 128 self-paired: p = |Z[128]|^2, rev4(128)=2
            float2 Z = zc[swz(2)];
            float p = fmaf(Z.x, Z.x, Z.y * Z.y);
            float u = ubuf[128];
            float ff = floorf(u);
            int   f  = (int)ff;
            float d  = u - ff;
            if (f >= 1 && f <= NMELS) atomicAdd(&acc[wv][f - 1], (1.0f - d) * p);
            if (f >= 0 && f <  NMELS) atomicAdd(&acc[wv][f],     d * p);
        }
    }

    // ---- log + stage for transposed write ----
    if (valid) {
        res[lane * FPB + wv] = __logf(fmaxf(acc[wv][lane], EPSV));
        if (lane < NMELS - 64)
            res[(64 + lane) * FPB + wv] = __logf(fmaxf(acc[wv][64 + lane], EPSV));
    }
    __syncthreads();

    // ---- transposed output, 8B bursts ----
    const int nval = min(FPB, NFRM - f0);
    if (tid < NMELS) {
        size_t o = ((size_t)bb * NMELS + tid) * NFRM + (size_t)f0;
        *(float2*)&out[o] = make_float2(res[tid * 4 + 0], res[tid * 4 + 1]);
        if (nval == 4)
            *(float2*)&out[o + 2] = make_float2(res[tid * 4 + 2], res[tid * 4 + 3]);
    }
}

extern "C" void kernel_launch(void* const* d_in, const int* in_sizes, int n_in,
                              void* d_out, int out_size, void* d_ws, size_t ws_size,
                              hipStream_t stream)
{
    const float* wav = (const float*)d_in[0];
    float* out = (float*)d_out;
    float* ws  = (float*)d_ws;
    if (ws != nullptr && ws_size >= WS_FLOATS * sizeof(float)) {
        setup_kernel<<<dim3(8), dim3(128), 0, stream>>>(ws);
        fbank_kernel<true><<<dim3(32 * BPB), dim3(256), 0, stream>>>(wav, out, ws);
    } else {
        fbank_kernel<false><<<dim3(32 * BPB), dim3(256), 0, stream>>>(wav, out, ws);
    }
}

// Round 6
// 54.345 us; speedup vs baseline: 2.4208x; 2.4208x over previous
//
#include <hip/hip_runtime.h>
#include <math.h>

#ifndef M_PI
#define M_PI 3.14159265358979323846
#endif

#define NWIN   400
#define NSHIFT 160
#define NMELS  80
#define NFRM   998
#define WLEN   160000
#define FPB    4
#define BPB    250          // frame-blocks per batch (249 full + 1 tail of 2)
#define EPSV   1.1920929e-07f
#define WCOLS  29           // mel weight row stride (gcd(29,32)=1 -> conflict-free)

// workspace layout (floats)
#define WIN_OFF  0      // [400]  Povey window
#define TWID_OFF 400    // [85*6] per-stage radix-4 twiddles
#define WEXP_OFF 912    // [128*2] untangle W[k]=e^{-i pi k/256} (cos,-sin)
#define MELB_OFF 1168   // [80] int2 (blo, span)
#define MELW_OFF 1328   // [80*29] mel triangle weights
#define WS_FLOATS 3648  // 14592 B

// XOR swizzle on complex (float2) slot index: all 4 FFT stages hit the
// 4-lane-per-bank-pair floor for b64.
__device__ __forceinline__ int swz(int s) { return s ^ ((s >> 4) & 15); }

__global__ __launch_bounds__(128)
void setup_kernel(float* __restrict__ ws)
{
    const int gid = blockIdx.x * 128 + threadIdx.x;   // grid 8 x 128
    const double ML = 1127.0 * log(1.0 + 20.0 / 700.0);
    const double MH = 1127.0 * log(1.0 + 8000.0 / 700.0);
    const double DD = (MH - ML) / (double)(NMELS + 1);

    if (gid < NWIN) {
        double a = 0.5 - 0.5 * cos(2.0 * M_PI * (double)gid / 399.0);
        if (a < 0.0) a = 0.0;
        ws[WIN_OFF + gid] = (float)pow(a, 0.85);
    } else if (gid >= 400 && gid < 485) {
        int e = gid - 400, st, j;
        if      (e < 64) { st = 0; j = e; }
        else if (e < 80) { st = 1; j = e - 64; }
        else if (e < 84) { st = 2; j = e - 80; }
        else             { st = 3; j = 0; }
        int Q = 64 >> (2 * st);
        double ang = -M_PI * (double)j / (2.0 * (double)Q);   // -2*pi*j/(4Q)
        float* t = ws + TWID_OFF + e * 6;
        t[0] = (float)cos(ang);       t[1] = (float)sin(ang);
        t[2] = (float)cos(2.0 * ang); t[3] = (float)sin(2.0 * ang);
        t[4] = (float)cos(3.0 * ang); t[5] = (float)sin(3.0 * ang);
    } else if (gid >= 512 && gid < 640) {
        int k = gid - 512;
        double th = M_PI * (double)k / 256.0;
        ws[WEXP_OFF + 2 * k]     = (float)cos(th);
        ws[WEXP_OFF + 2 * k + 1] = (float)(-sin(th));
    } else if (gid >= 640 && gid < 640 + NMELS) {
        int j = gid - 640;
        double mlo = ML + (double)j * DD;
        double mhi = mlo + 2.0 * DD;
        double flo = 700.0 * (exp(mlo / 1127.0) - 1.0);
        double fhi = 700.0 * (exp(mhi / 1127.0) - 1.0);
        int blo = max(1,   (int)(flo / 31.25));        // +-1 slack: weight clamps to 0
        int bhi = min(255, (int)(fhi / 31.25) + 1);
        int span = min(bhi - blo + 1, WCOLS);
        ((int2*)(ws + MELB_OFF))[j] = make_int2(blo, span);
        for (int i = 0; i < span; ++i) {
            int b = blo + i;
            double u = (1127.0 * log(1.0 + (double)b * 31.25 / 700.0) - ML) / DD;
            double w = fmin(u - (double)j, (double)(j + 2) - u);
            ws[MELW_OFF + j * WCOLS + i] = (float)fmax(w, 0.0);
        }
    }
}

template<bool USE_TAB>
__global__ __launch_bounds__(256)
void fbank_kernel(const float* __restrict__ wav, float* __restrict__ out,
                  const float* __restrict__ ws)
{
    __shared__ __align__(16) float zbf[FPB][512];        // per-wave complex buffer
    __shared__ __align__(16) float pbuf[FPB][256];       // power spectrum
    __shared__ __align__(16) float wbuf[NWIN];           // Povey window
    __shared__ __align__(16) float wtab[NMELS * WCOLS];  // mel weights
    __shared__ __align__(16) int2  melb[NMELS];          // (blo, span)
    __shared__ __align__(16) float res[NMELS * FPB];     // logmel [mel][frame-slot]

    const int tid  = threadIdx.x;
    const int lane = tid & 63;
    const int wv   = tid >> 6;                 // one wave per frame
    const int bb   = blockIdx.x / BPB;
    const int f0   = (blockIdx.x % BPB) * FPB;
    const bool valid = (f0 + wv) < NFRM;

    // ---- tables: stage from workspace, or (fallback) fast-intrinsic build ----
    if constexpr (USE_TAB) {
        wbuf[tid] = ws[WIN_OFF + tid];
        if (tid < NWIN - 256) wbuf[tid + 256] = ws[WIN_OFF + 256 + tid];
        for (int i = tid; i < NMELS * WCOLS; i += 256) wtab[i] = ws[MELW_OFF + i];
        if (tid < NMELS) melb[tid] = ((const int2*)(ws + MELB_OFF))[tid];
    } else {
        const float MLf = 1127.0f * __logf(1.0f + 20.0f / 700.0f);
        const float MHf = 1127.0f * __logf(1.0f + 8000.0f / 700.0f);
        const float DDf = (MHf - MLf) / (float)(NMELS + 1);
        const float CW = (float)(2.0 * M_PI / 399.0);
        float a = fmaxf(0.5f - 0.5f * __cosf((float)tid * CW), 0.0f);
        wbuf[tid] = __powf(a, 0.85f);
        if (tid < NWIN - 256) {
            int n = tid + 256;
            float a2 = fmaxf(0.5f - 0.5f * __cosf((float)n * CW), 0.0f);
            wbuf[n] = __powf(a2, 0.85f);
        }
        if (tid < NMELS) {
            int j = tid;
            float mlo = MLf + (float)j * DDf;
            float mhi = mlo + 2.0f * DDf;
            float flo = 700.0f * (__expf(mlo * (1.0f / 1127.0f)) - 1.0f);
            float fhi = 700.0f * (__expf(mhi * (1.0f / 1127.0f)) - 1.0f);
            int blo = max(1,   (int)(flo * (1.0f / 31.25f)));
            int bhi = min(255, (int)(fhi * (1.0f / 31.25f)) + 1);
            int span = min(bhi - blo + 1, WCOLS);
            melb[j] = make_int2(blo, span);
            for (int i = 0; i < span; ++i) {
                int b = blo + i;
                float u = (1127.0f * __logf(1.0f + (float)b * (31.25f / 700.0f)) - MLf) / DDf;
                wtab[j * WCOLS + i] = fmaxf(0.0f, fminf(u - (float)j, (float)(j + 2) - u));
            }
        }
    }
    __syncthreads();

    float*  zf = zbf[wv];
    float2* zc = (float2*)zf;

    // ---- preprocess: de-mean, pre-emphasis (2nd load), window; pack pairs ----
    if (valid) {
        const float* xp = wav + (size_t)bb * WLEN + (size_t)(f0 + wv) * NSHIFT;
        float xc[7], xm[7];
        float s = 0.0f;
        #pragma unroll
        for (int t = 0; t < 7; ++t) {
            int n = 64 * t + lane;
            bool vn = (t < 6 || lane < 16);
            xc[t] = vn ? xp[n] : 0.0f;
            xm[t] = (vn && n > 0) ? xp[n - 1] : 0.0f;   // L1-hit reload
            s += xc[t];
        }
        if (lane == 0) xm[0] = xc[0];                   // ref: prev[0] = x[0]
        #pragma unroll
        for (int off = 32; off > 0; off >>= 1) s += __shfl_xor(s, off, 64);
        const float mu3 = 0.03f * (s * (1.0f / (float)NWIN));
        #pragma unroll
        for (int t = 0; t < 7; ++t) {
            int n = 64 * t + lane;
            float y = 0.0f;
            if (t < 6 || lane < 16)
                y = (fmaf(-0.97f, xm[t], xc[t]) - mu3) * wbuf[n];
            zf[(swz(n >> 1) << 1) | (n & 1)] = y;       // n>=400 slots get 0
        }
        zf[(swz((448 + lane) >> 1) << 1) | (lane & 1)] = 0.0f;  // pad z[224..255]
    }

    // ---- 256-point radix-4 DIF FFT, in-place, digit-reversed output ----
    // Wave-private LDS: same-wave DS ordering + compiler lgkmcnt suffice.
    if (valid) {
        #pragma unroll
        for (int st = 0; st < 4; ++st) {
            const int Q = 64 >> (2 * st);                 // L/4
            int j  = lane & (Q - 1);
            int i0 = ((lane & ~(Q - 1)) << 2) + j;        // base + j
            float2 a0 = zc[swz(i0)];
            float2 a1 = zc[swz(i0 + Q)];
            float2 a2 = zc[swz(i0 + 2 * Q)];
            float2 a3 = zc[swz(i0 + 3 * Q)];
            float t0x = a0.x + a2.x, t0y = a0.y + a2.y;
            float t1x = a1.x + a3.x, t1y = a1.y + a3.y;
            float t2x = a0.x - a2.x, t2y = a0.y - a2.y;
            float t3x = a1.x - a3.x, t3y = a1.y - a3.y;
            float b0x = t0x + t1x, b0y = t0y + t1y;       // q=0
            float b2x = t0x - t1x, b2y = t0y - t1y;       // q=2
            float b1x = t2x + t3y, b1y = t2y - t3x;       // q=1: t2 - i*t3
            float b3x = t2x - t3y, b3y = t2y + t3x;       // q=3: t2 + i*t3
            float cn, sn, w2x, w2y, w3x, w3y;
            if constexpr (USE_TAB) {
                constexpr int TOFF[4] = {0, 64, 80, 84};
                const float* tw = ws + TWID_OFF + (TOFF[st] + j) * 6;
                cn = tw[0]; sn = tw[1]; w2x = tw[2]; w2y = tw[3]; w3x = tw[4]; w3y = tw[5];
            } else {
                float ang = (float)j * (float)(-M_PI / 2.0 / (double)Q);
                __sincosf(ang, &sn, &cn);
                w2x = cn * cn - sn * sn; w2y = 2.0f * cn * sn;
                w3x = w2x * cn - w2y * sn; w3y = w2x * sn + w2y * cn;
            }
            zc[swz(i0)]       = make_float2(b0x, b0y);
            zc[swz(i0 + Q)]   = make_float2(fmaf(b1x, cn,  -b1y * sn),  fmaf(b1x, sn,  b1y * cn));
            zc[swz(i0 + 2*Q)] = make_float2(fmaf(b2x, w2x, -b2y * w2y), fmaf(b2x, w2y, b2y * w2x));
            zc[swz(i0 + 3*Q)] = make_float2(fmaf(b3x, w3x, -b3y * w3y), fmaf(b3x, w3y, b3y * w3x));
        }
    }

    // ---- pair-symmetric untangle + power ----
    // X[k] = E + W*O, X[256-k] = conj(E - W*O); p = |X|^2.
    if (valid) {
        const int rl = ((lane & 3) << 6) | (((lane >> 2) & 3) << 4) | (((lane >> 4) & 3) << 2);
        #pragma unroll
        for (int r = 0; r < 2; ++r) {
            int k  = 64 * r + lane;
            int m8 = (256 - k) & 255;
            int rk = rl | r;
            int rm = ((m8 & 3) << 6) | (((m8 >> 2) & 3) << 4) | (((m8 >> 4) & 3) << 2) | ((m8 >> 6) & 3);
            float2 Zk = zc[swz(rk)];
            float2 Zm = zc[swz(rm)];
            float Sx = Zk.x + Zm.x, Sy = Zk.y - Zm.y;   // 2E
            float Ox = Zk.y + Zm.y, Oy = Zm.x - Zk.x;   // 2O
            float Wx, Wy;
            if constexpr (USE_TAB) {
                float2 w = ((const float2*)(ws + WEXP_OFF))[k];
                Wx = w.x; Wy = w.y;
            } else {
                __sincosf((float)k * (float)(-M_PI / 256.0), &Wy, &Wx);
            }
            float Ux = fmaf(Wx, Ox, -Wy * Oy), Uy = fmaf(Wx, Oy, Wy * Ox);  // 2*W*O
            float q1 = Sx + Ux, q2 = Sy + Uy;
            float q3 = Sx - Ux, q4 = Sy - Uy;
            pbuf[wv][k] = 0.25f * fmaf(q1, q1, q2 * q2);
            if (m8 != 0)                                  // m8==0 <=> bin 256 (weight 0)
                pbuf[wv][m8] = 0.25f * fmaf(q3, q3, q4 * q4);
        }
        if (lane == 0) {   // bin 128 self-paired: |X|^2 = |Z[128]|^2, rev4(128)=2
            float2 Z = zc[swz(2)];
            pbuf[wv][128] = fmaf(Z.x, Z.x, Z.y * Z.y);
        }
    }

    // ---- mel gather (balanced lane->mel map) + log ----
    // loop A: lanes 0-15 -> wide mels 64..79; lanes 16-63 -> mels 16..63
    // loop B: lanes 0-15 -> narrow mels 0..15 (1-2 bins each)
    if (valid) {
        {
            int j = (lane < 16) ? (64 + lane) : lane;
            int2 mb = melb[j];
            const float* wrow = &wtab[j * WCOLS];
            float acc = 0.0f;
            for (int i = 0; i < mb.y; ++i)
                acc = fmaf(wrow[i], pbuf[wv][mb.x + i], acc);
            res[j * FPB + wv] = __logf(fmaxf(acc, EPSV));
        }
        if (lane < 16) {
            int j = lane;
            int2 mb = melb[j];
            const float* wrow = &wtab[j * WCOLS];
            float acc = 0.0f;
            for (int i = 0; i < mb.y; ++i)
                acc = fmaf(wrow[i], pbuf[wv][mb.x + i], acc);
            res[j * FPB + wv] = __logf(fmaxf(acc, EPSV));
        }
    }
    __syncthreads();

    // ---- transposed output, 8B bursts ----
    const int nval = min(FPB, NFRM - f0);
    if (tid < NMELS) {
        size_t o = ((size_t)bb * NMELS + tid) * NFRM + (size_t)f0;
        *(float2*)&out[o] = make_float2(res[tid * 4 + 0], res[tid * 4 + 1]);
        if (nval == 4)
            *(float2*)&out[o + 2] = make_float2(res[tid * 4 + 2], res[tid * 4 + 3]);
    }
}

extern "C" void kernel_launch(void* const* d_in, const int* in_sizes, int n_in,
                              void* d_out, int out_size, void* d_ws, size_t ws_size,
                              hipStream_t stream)
{
    const float* wav = (const float*)d_in[0];
    float* out = (float*)d_out;
    float* ws  = (float*)d_ws;
    if (ws != nullptr && ws_size >= WS_FLOATS * sizeof(float)) {
        setup_kernel<<<dim3(8), dim3(128), 0, stream>>>(ws);
        fbank_kernel<true><<<dim3(32 * BPB), dim3(256), 0, stream>>>(wav, out, ws);
    } else {
        fbank_kernel<false><<<dim3(32 * BPB), dim3(256), 0, stream>>>(wav, out, ws);
    }
}